// Round 1
// baseline (189.809 us; speedup 1.0000x reference)
//
#include <hip/hip_runtime.h>

// ---- Geometry / model constants (match reference) ----
#define GXv 352
#define GYv 400
#define BATCH 2
#define NSEG (BATCH * GYv * GXv)   // 281600
#define C_OUT 64

__constant__ float kVX = 0.2f;
__constant__ float kVY = 0.2f;

static constexpr float VXc = 0.2f;
static constexpr float VYc = 0.2f;
static constexpr float X_OFF = 0.1f;            // VX/2 + pcr[0]
static constexpr float Y_OFF = -39.9f;          // VY/2 + pcr[1]
static constexpr float EPS = 1e-3f;

// Stage 1: per-voxel (sum_x, sum_y, sum_z, count) into ws as float4
__global__ void scatter_sum_kernel(const float* __restrict__ feat,
                                   const int*  __restrict__ coors,
                                   float*      __restrict__ ws,   // [NSEG*4]
                                   int n) {
    int i = blockIdx.x * blockDim.x + threadIdx.x;
    if (i >= n) return;
    int4 c = ((const int4*)coors)[i];          // (b, z, y, x)
    float4 f = ((const float4*)feat)[i];       // (x, y, z, r)
    int idx = c.x * (GYv * GXv) + c.z * GXv + c.w;
    float* p = ws + idx * 4;
    atomicAdd(p + 0, f.x);
    atomicAdd(p + 1, f.y);
    atomicAdd(p + 2, f.z);
    atomicAdd(p + 3, 1.0f);
}

// Stage 2: 64 threads per point; lane j computes output channel j,
// then scatter-max into the dense canvas via uint atomicMax (h >= 0).
__global__ void pfn_forward_kernel(const float* __restrict__ feat,
                                   const int*  __restrict__ coors,
                                   const float4* __restrict__ ws,   // [NSEG]
                                   const float* __restrict__ W,     // [9,64] row-major
                                   const float* __restrict__ gamma,
                                   const float* __restrict__ beta,
                                   const float* __restrict__ rmean,
                                   const float* __restrict__ rvar,
                                   float*       __restrict__ out,   // [NSEG,64]
                                   int n) {
    int gid = blockIdx.x * blockDim.x + threadIdx.x;
    int i = gid >> 6;       // point
    int j = gid & 63;       // output channel
    if (i >= n) return;

    float4 f = ((const float4*)feat)[i];       // broadcast within the 64-lane group
    int4   c = ((const int4*)coors)[i];
    int idx = c.x * (GYv * GXv) + c.z * GXv + c.w;
    float4 s = ws[idx];

    float inv = 1.0f / fmaxf(s.w, 1.0f);
    float feats[9];
    feats[0] = f.x;
    feats[1] = f.y;
    feats[2] = f.z;
    feats[3] = f.w;
    feats[4] = f.x - s.x * inv;                // f_cluster
    feats[5] = f.y - s.y * inv;
    feats[6] = f.z - s.z * inv;
    feats[7] = f.x - ((float)c.w * VXc + X_OFF);  // f_center x
    feats[8] = f.y - ((float)c.z * VYc + Y_OFF);  // f_center y

    float acc = 0.0f;
    #pragma unroll
    for (int k = 0; k < 9; ++k)
        acc = fmaf(feats[k], W[k * C_OUT + j], acc);

    float scale = gamma[j] * rsqrtf(rvar[j] + EPS);
    float h = (acc - rmean[j]) * scale + beta[j];
    h = fmaxf(h, 0.0f);   // ReLU -> h >= 0, so uint-bit atomicMax is valid

    atomicMax((unsigned int*)(out + (size_t)idx * C_OUT + j), __float_as_uint(h));
}

extern "C" void kernel_launch(void* const* d_in, const int* in_sizes, int n_in,
                              void* d_out, int out_size, void* d_ws, size_t ws_size,
                              hipStream_t stream) {
    const float* feat  = (const float*)d_in[0];
    const int*   coors = (const int*)d_in[1];
    const float* W     = (const float*)d_in[2];
    const float* gamma = (const float*)d_in[3];
    const float* beta  = (const float*)d_in[4];
    const float* rmean = (const float*)d_in[5];
    const float* rvar  = (const float*)d_in[6];
    float* out = (float*)d_out;

    const int n = in_sizes[0] / 4;   // N points (features is [N,4])

    // Zero the voxel-sum workspace (NSEG float4) and the output canvas.
    hipMemsetAsync(d_ws, 0, (size_t)NSEG * 4 * sizeof(float), stream);
    hipMemsetAsync(d_out, 0, (size_t)out_size * sizeof(float), stream);

    {
        dim3 blk(256);
        dim3 grd((n + 255) / 256);
        scatter_sum_kernel<<<grd, blk, 0, stream>>>(feat, coors, (float*)d_ws, n);
    }
    {
        dim3 blk(256);
        long long total = (long long)n * C_OUT;
        dim3 grd((unsigned)((total + 255) / 256));
        pfn_forward_kernel<<<grd, blk, 0, stream>>>(feat, coors, (const float4*)d_ws,
                                                    W, gamma, beta, rmean, rvar,
                                                    out, n);
    }
}

// Round 3
// 145.580 us; speedup vs baseline: 1.3038x; 1.3038x over previous
//
#include <hip/hip_runtime.h>

// ---- Geometry / model constants (match reference) ----
#define GXv 352
#define GYv 400
#define BATCH 2
#define NSEG (BATCH * GYv * GXv)   // 281600
#define C_OUT 64
#define SCAN_BLK 256
#define NBLK1 (NSEG / SCAN_BLK)    // 1100 (NSEG divisible by 256)

static constexpr float VXc   = 0.2f;
static constexpr float VYc   = 0.2f;
static constexpr float X_OFF = 0.1f;     // VX/2 + pcr[0]
static constexpr float Y_OFF = -39.9f;   // VY/2 + pcr[1]
static constexpr float EPSc  = 1e-3f;

// ws layout (ints):
//   counts [NSEG]            @ 0
//   offs   [NSEG]            @ NSEG
//   cur    [NSEG]            @ 2*NSEG
//   bsums  [2048 pad]        @ 3*NSEG
//   plist  [N]               @ 3*NSEG + 2048
#define WS_COUNTS 0
#define WS_OFFS   (NSEG)
#define WS_CUR    (2 * NSEG)
#define WS_BSUMS  (3 * NSEG)
#define WS_PLIST  (3 * NSEG + 2048)

// P2: histogram points per voxel
__global__ void k_count(const int4* __restrict__ coors, int* __restrict__ counts, int n) {
    int i = blockIdx.x * blockDim.x + threadIdx.x;
    if (i >= n) return;
    int4 c = coors[i];                              // (b, z, y, x)
    int v = c.x * (GYv * GXv) + c.z * GXv + c.w;
    atomicAdd(&counts[v], 1);
}

// P3a: per-256-block exclusive scan; block totals to bsums
__global__ void k_scan1(const int* __restrict__ counts, int* __restrict__ offs,
                        int* __restrict__ bsums) {
    __shared__ int s[SCAN_BLK];
    int t = threadIdx.x;
    int g = blockIdx.x * SCAN_BLK + t;
    int v = (g < NSEG) ? counts[g] : 0;
    s[t] = v;
    __syncthreads();
    #pragma unroll
    for (int d = 1; d < SCAN_BLK; d <<= 1) {
        int x = (t >= d) ? s[t - d] : 0;
        __syncthreads();
        s[t] += x;
        __syncthreads();
    }
    int incl = s[t];
    if (g < NSEG) offs[g] = incl - v;
    if (t == SCAN_BLK - 1) bsums[blockIdx.x] = incl;
}

// P3b: single-block scan of the 1100 block sums (exclusive)
__global__ void k_scan2(int* __restrict__ bsums, int nb) {
    __shared__ int s[SCAN_BLK];
    __shared__ int carry_s;
    int t = threadIdx.x;
    if (t == 0) carry_s = 0;
    __syncthreads();
    for (int base = 0; base < nb; base += SCAN_BLK) {
        int g = base + t;
        int v = (g < nb) ? bsums[g] : 0;
        s[t] = v;
        __syncthreads();
        #pragma unroll
        for (int d = 1; d < SCAN_BLK; d <<= 1) {
            int x = (t >= d) ? s[t - d] : 0;
            __syncthreads();
            s[t] += x;
            __syncthreads();
        }
        int carry = carry_s;
        int incl = s[t];
        if (g < nb) bsums[g] = incl - v + carry;   // exclusive + carry
        __syncthreads();
        if (t == SCAN_BLK - 1) carry_s = carry + incl;
        __syncthreads();
    }
}

// P3c: add scanned block sums -> final exclusive offsets
__global__ void k_scan3(int* __restrict__ offs, const int* __restrict__ bsums) {
    int g = blockIdx.x * blockDim.x + threadIdx.x;
    if (g < NSEG) offs[g] += bsums[g >> 8];       // blockDim == 256
}

// P4: fill CSR point list
__global__ void k_fill(const int4* __restrict__ coors, const int* __restrict__ offs,
                       int* __restrict__ cur, int* __restrict__ plist, int n) {
    int i = blockIdx.x * blockDim.x + threadIdx.x;
    if (i >= n) return;
    int4 c = coors[i];
    int v = c.x * (GYv * GXv) + c.z * GXv + c.w;
    int pos = atomicAdd(&cur[v], 1);
    plist[offs[v] + pos] = i;
}

// P5: per-voxel gather -> mean -> Linear+BN+ReLU -> max -> coalesced store.
// 64 lanes = 64 output channels per voxel; grid-stride over voxels.
__global__ __launch_bounds__(256) void k_out(
        const float4* __restrict__ feat,
        const int*  __restrict__ offs,
        const int*  __restrict__ counts,
        const int*  __restrict__ plist,
        const float* __restrict__ W,      // [9,64]
        const float* __restrict__ gamma,
        const float* __restrict__ beta,
        const float* __restrict__ rmean,
        const float* __restrict__ rvar,
        float* __restrict__ out) {        // [NSEG,64]
    int t = blockIdx.x * blockDim.x + threadIdx.x;
    int j = t & 63;                       // channel
    int slot = t >> 6;                    // voxel slot (wave-uniform)
    int nslots = (gridDim.x * blockDim.x) >> 6;

    float scale = gamma[j] * rsqrtf(rvar[j] + EPSc);
    float shift = beta[j] - rmean[j] * scale;
    float w[9];
    #pragma unroll
    for (int k = 0; k < 9; ++k) w[k] = W[k * C_OUT + j] * scale;

    for (int v = slot; v < NSEG; v += nslots) {
        int cnt = counts[v];
        float res = 0.0f;
        if (cnt > 0) {
            int off = offs[v];
            int xy = v % (GYv * GXv);
            int y = xy / GXv;
            int x = xy - y * GXv;
            float cx = (float)x * VXc + X_OFF;
            float cy = (float)y * VYc + Y_OFF;

            float sx = 0.f, sy = 0.f, sz = 0.f;
            for (int p = 0; p < cnt; ++p) {
                float4 f = feat[plist[off + p]];
                sx += f.x; sy += f.y; sz += f.z;
            }
            float inv = 1.0f / (float)cnt;
            float mx = sx * inv, my = sy * inv, mz = sz * inv;

            float m = -1e30f;
            for (int p = 0; p < cnt; ++p) {
                float4 f = feat[plist[off + p]];   // L1-hot (just read)
                float acc =      f.x       * w[0];
                acc = fmaf(      f.y,        w[1], acc);
                acc = fmaf(      f.z,        w[2], acc);
                acc = fmaf(      f.w,        w[3], acc);
                acc = fmaf(f.x - mx,         w[4], acc);
                acc = fmaf(f.y - my,         w[5], acc);
                acc = fmaf(f.z - mz,         w[6], acc);
                acc = fmaf(f.x - cx,         w[7], acc);
                acc = fmaf(f.y - cy,         w[8], acc);
                m = fmaxf(m, acc + shift);
            }
            res = fmaxf(m, 0.0f);          // ReLU after max (monotone)
        }
        out[(size_t)v * C_OUT + j] = res;
    }
}

extern "C" void kernel_launch(void* const* d_in, const int* in_sizes, int n_in,
                              void* d_out, int out_size, void* d_ws, size_t ws_size,
                              hipStream_t stream) {
    const float* feat  = (const float*)d_in[0];
    const int*   coors = (const int*)d_in[1];
    const float* W     = (const float*)d_in[2];
    const float* gamma = (const float*)d_in[3];
    const float* beta  = (const float*)d_in[4];
    const float* rmean = (const float*)d_in[5];
    const float* rvar  = (const float*)d_in[6];
    float* out = (float*)d_out;

    const int n = in_sizes[0] / 4;        // N points

    int* ws = (int*)d_ws;
    int* counts = ws + WS_COUNTS;
    int* offs   = ws + WS_OFFS;
    int* cur    = ws + WS_CUR;
    int* bsums  = ws + WS_BSUMS;
    int* plist  = ws + WS_PLIST;

    // Zero counts/offs/cur/bsums in one shot (plist needs no init)
    hipMemsetAsync(ws, 0, (size_t)(3 * NSEG + 2048) * sizeof(int), stream);

    const int nb = NBLK1;                 // 1100
    dim3 blk(256);
    k_count<<<dim3((n + 255) / 256), blk, 0, stream>>>((const int4*)coors, counts, n);
    k_scan1<<<dim3(nb), blk, 0, stream>>>(counts, offs, bsums);
    k_scan2<<<dim3(1),  blk, 0, stream>>>(bsums, nb);
    k_scan3<<<dim3(nb), blk, 0, stream>>>(offs, bsums);
    k_fill <<<dim3((n + 255) / 256), blk, 0, stream>>>((const int4*)coors, offs, cur, plist, n);
    k_out  <<<dim3(2048), blk, 0, stream>>>((const float4*)feat, offs, counts, plist,
                                            W, gamma, beta, rmean, rvar, out);
}